// Round 2
// baseline (334.958 us; speedup 1.0000x reference)
//
#include <hip/hip_runtime.h>
#include <math.h>

#define M_TOTAL (32 * 8732)     // 279424 anchors, divisible by 64
#define NBLK_A (M_TOTAL / 64)   // 4366 blocks

struct Scalars {
    unsigned pos_num;
    float    loss_l;   // masked smooth-L1 sum
    float    pos_lc;   // sum of loss_c over positives
};

__device__ __forceinline__ float smooth_l1(float d) {
    float ad = fabsf(d);
    return (ad < 1.0f) ? 0.5f * ad * ad : ad - 0.5f;
}

// async global->LDS, 16B per lane; LDS dest = wave-uniform base + lane*16
#define GLLDS16(gp, lp) __builtin_amdgcn_global_load_lds( \
    (__attribute__((address_space(1))) void*)(gp),        \
    (__attribute__((address_space(3))) void*)(lp), 16, 0, 0)

// ---- Kernel A: CE + smooth-L1 + con_neg + level-0 histogram ----
// 4 waves/block; each wave stages its 16 rows (16*324B = 5184B contiguous,
// 16B-aligned since 5184%16==0) into LDS via global_load_lds, then 4 lanes
// per anchor compute logsumexp from LDS.
__global__ __launch_bounds__(256) void kA(const float* __restrict__ ploc,
                                          const float* __restrict__ plabel,
                                          const float* __restrict__ gloc,
                                          const int* __restrict__ glabel,
                                          float* __restrict__ con_neg,
                                          unsigned* __restrict__ hist0,
                                          Scalars* sc) {
    __shared__ __align__(16) float stage[4 * 1296];  // 4 waves * 16 rows * 81 floats
    __shared__ unsigned lh[2048];
    __shared__ float    redf[4][2];
    __shared__ unsigned redp[4];

    const int tid  = threadIdx.x;
    const int w    = tid >> 6;
    const int lane = tid & 63;
    const int g    = lane >> 2;   // anchor within wave (0..15)
    const int l    = lane & 3;    // lane within anchor group

    for (int i = tid; i < 2048; i += 256) lh[i] = 0u;

    const size_t wrow0 = (size_t)blockIdx.x * 64 + (size_t)w * 16;
    const char*  gsrc  = (const char*)(plabel + wrow0 * 81);
    char*        ldst  = (char*)&stage[w * 1296];

    // 5 x 1KB + 64B tail = 5184B per wave, all 16B-aligned
#pragma unroll
    for (int j = 0; j < 5; ++j)
        GLLDS16(gsrc + (size_t)j * 1024 + (size_t)lane * 16, ldst + j * 1024);
    if (lane < 4)
        GLLDS16(gsrc + 5120 + (size_t)lane * 16, ldst + 5120);

    const size_t row = wrow0 + g;
    // coalesced: 64 consecutive dwords per wave
    const float pl = ploc[wrow0 * 4 + lane];
    const float gl = gloc[wrow0 * 4 + lane];
    int gt = 0;
    if (l == 0) gt = glabel[row];
    const int mask = gt > 0;

    float s = smooth_l1(pl - gl);
    s += __shfl_xor(s, 1);
    s += __shfl_xor(s, 2);

    __syncthreads();   // drains vmcnt (global_load_lds) + orders lh zeroing

    const float* rowp = &stage[w * 1296 + g * 81];
    float v[20];
    float m = -INFINITY;
#pragma unroll
    for (int j = 0; j < 20; ++j) { v[j] = rowp[j * 4 + l]; m = fmaxf(m, v[j]); }
    float v80 = 0.0f;
    if (l == 0) { v80 = rowp[80]; m = fmaxf(m, v80); }
    m = fmaxf(m, __shfl_xor(m, 1));
    m = fmaxf(m, __shfl_xor(m, 2));

    float e = 0.0f;
#pragma unroll
    for (int j = 0; j < 20; ++j) e += __expf(v[j] - m);
    if (l == 0) e += __expf(v80 - m);
    e += __shfl_xor(e, 1);
    e += __shfl_xor(e, 2);
    const float lse = m + __logf(e);

    float wl = 0.0f, wc = 0.0f, wp = 0.0f;
    if (l == 0) {
        const float x_gt   = rowp[gt];
        const float loss_c = lse - x_gt;
        const float cn     = mask ? 0.0f : fmaxf(loss_c, 0.0f);
        con_neg[row] = cn;                       // 16 consecutive dwords/wave
        atomicAdd(&lh[__float_as_uint(cn) >> 21], 1u);
        if (mask) { wl = s; wc = loss_c; wp = 1.0f; }
    }
    // wave-reduce the 16 group values (nonzero only on l==0 lanes)
#pragma unroll
    for (int off = 4; off < 64; off <<= 1) {
        wl += __shfl_xor(wl, off);
        wc += __shfl_xor(wc, off);
        wp += __shfl_xor(wp, off);
    }
    if (lane == 0) { redf[w][0] = wl; redf[w][1] = wc; redp[w] = (unsigned)wp; }
    __syncthreads();

    if (tid == 0) {
        const float    sl  = redf[0][0] + redf[1][0] + redf[2][0] + redf[3][0];
        const float    sc2 = redf[0][1] + redf[1][1] + redf[2][1] + redf[3][1];
        const unsigned pn  = redp[0] + redp[1] + redp[2] + redp[3];
        if (pn) atomicAdd(&sc->pos_num, pn);
        atomicAdd(&sc->loss_l, sl);
        atomicAdd(&sc->pos_lc, sc2);
    }
    for (int i = tid; i < 2048; i += 256) {
        const unsigned c = lh[i];
        if (c) atomicAdd(&hist0[i], c);
    }
}

// ---- block-wide suffix-scan select: find bin with suffix(b) >= k > suffix(b+1)
__device__ __forceinline__ void suffix_select(const unsigned* h, unsigned* ssum,
                                              int nbins, unsigned k,
                                              unsigned* rbin, unsigned* rk) {
    const int t = threadIdx.x;
    const unsigned h0 = (2 * t < nbins) ? h[2 * t] : 0u;
    const unsigned h1 = (2 * t + 1 < nbins) ? h[2 * t + 1] : 0u;
    ssum[t] = h0 + h1;
    __syncthreads();
    for (int off = 1; off < 1024; off <<= 1) {
        const unsigned val = ssum[t];
        const unsigned add = (t + off < 1024) ? ssum[t + off] : 0u;
        __syncthreads();
        ssum[t] = val + add;
        __syncthreads();
    }
    const unsigned sA = ssum[t];
    const unsigned sB = sA - h0;
    const unsigned sC = (t + 1 < 1024) ? ssum[t + 1] : 0u;
    if (k > 0u) {
        if (2 * t < nbins && sA >= k && k > sB) { *rbin = 2u * (unsigned)t;      *rk = k - sB; }
        if (2 * t + 1 < nbins && sB >= k && k > sC) { *rbin = 2u * (unsigned)t + 1u; *rk = k - sC; }
    }
    __syncthreads();
}

// ---- Kernel B: entire selection + final sum + output in ONE launch ----
// single 1024-thread block; con is only 1.1MB (L2-hot).
__global__ __launch_bounds__(1024) void kSel(const float* __restrict__ con,
                                             const unsigned* __restrict__ hist0,
                                             const Scalars* __restrict__ sc,
                                             float* __restrict__ out) {
    __shared__ unsigned h[2048];
    __shared__ unsigned ssum[1024];
    __shared__ unsigned rbin, rk;
    __shared__ float    wred[16];
    const int t = threadIdx.x;

    const unsigned pn = sc->pos_num;
    unsigned k0 = 3u * pn;
    if (k0 > (unsigned)M_TOTAL) k0 = (unsigned)M_TOTAL;

    if (t == 0) { rbin = 0u; rk = 0u; }
    h[t]        = hist0[t];
    h[t + 1024] = hist0[t + 1024];
    __syncthreads();
    suffix_select(h, ssum, 2048, k0, &rbin, &rk);
    const unsigned b0 = rbin, k1 = rk;
    __syncthreads();

    // pass 1: hist of (u>>10) for bucket b0; accumulate sum of strictly-above buckets
    h[t] = 0u; h[t + 1024] = 0u;
    __syncthreads();
    float sum_hi = 0.0f;
    const float4* c4 = (const float4*)con;
    for (int i = t; i < M_TOTAL / 4; i += 1024) {
        const float4 q = c4[i];
        const float xs[4] = {q.x, q.y, q.z, q.w};
#pragma unroll
        for (int j = 0; j < 4; ++j) {
            const unsigned u  = __float_as_uint(xs[j]);
            const unsigned hi = u >> 21;
            if (hi > b0) sum_hi += xs[j];
            else if (hi == b0) atomicAdd(&h[(u >> 10) & 0x7FFu], 1u);
        }
    }
    __syncthreads();
    suffix_select(h, ssum, 2048, k1, &rbin, &rk);
    const unsigned b1 = rbin, k2 = rk;
    __syncthreads();

    // pass 2: exact low-10-bit hist within (b0,b1); accumulate mid-level above-sum
    h[t] = 0u;   // only bins 0..1023 used at level 2
    __syncthreads();
    const unsigned pref = (b0 << 11) | b1;
    for (int i = t; i < M_TOTAL / 4; i += 1024) {
        const float4 q = c4[i];
        const float xs[4] = {q.x, q.y, q.z, q.w};
#pragma unroll
        for (int j = 0; j < 4; ++j) {
            const unsigned u = __float_as_uint(xs[j]);
            if ((u >> 21) == b0) {
                const unsigned mid = (u >> 10) & 0x7FFu;
                if (mid > b1) sum_hi += xs[j];
                else if (mid == b1) atomicAdd(&h[u & 0x3FFu], 1u);
            }
        }
    }
    __syncthreads();
    suffix_select(h, ssum, 1024, k2, &rbin, &rk);
    const unsigned ct = rbin, r = rk;

    // in-bucket bins strictly above ct: level-2 bin IS the exact bit pattern
    if ((unsigned)t > ct) {
        const unsigned c = h[t];
        if (c) sum_hi += (float)c * __uint_as_float((pref << 10) | (unsigned)t);
    }

    // block reduce sum_hi
    float v = sum_hi;
#pragma unroll
    for (int off = 1; off < 64; off <<= 1) v += __shfl_xor(v, off);
    if ((t & 63) == 0) wred[t >> 6] = v;
    __syncthreads();
    if (t == 0) {
        float total_neg = 0.0f;
        for (int i = 0; i < 16; ++i) total_neg += wred[i];
        float outv = 0.0f;
        if (pn > 0u) {
            const float tval  = __uint_as_float((pref << 10) | ct);
            const float closs = sc->pos_lc + total_neg + (float)r * tval;
            outv = (sc->loss_l + closs) / (float)pn;
        }
        out[0] = outv;
    }
}

extern "C" void kernel_launch(void* const* d_in, const int* in_sizes, int n_in,
                              void* d_out, int out_size, void* d_ws, size_t ws_size,
                              hipStream_t stream) {
    const float* ploc   = (const float*)d_in[0];
    const float* plabel = (const float*)d_in[1];
    const float* gloc   = (const float*)d_in[2];
    const int*   glabel = (const int*)d_in[3];
    float* out = (float*)d_out;

    char* ws = (char*)d_ws;
    float*    con   = (float*)ws;                              // M floats
    unsigned* hist0 = (unsigned*)(ws + (size_t)M_TOTAL * 4);   // 2048 bins
    Scalars*  sc    = (Scalars*)(hist0 + 2048);

    hipMemsetAsync(hist0, 0, 2048 * sizeof(unsigned) + sizeof(Scalars), stream);
    kA<<<NBLK_A, 256, 0, stream>>>(ploc, plabel, gloc, glabel, con, hist0, sc);
    kSel<<<1, 1024, 0, stream>>>(con, hist0, sc, out);
}